// Round 1
// baseline (927.372 us; speedup 1.0000x reference)
//
#include <hip/hip_runtime.h>
#include <hip/hip_bf16.h>

// Qwen3VLMoeTextExpertsTransposed: E=32,H=2048,I=768,K=4,T=2048
#define E_ 32
#define H_ 2048
#define I_ 768
#define T_ 2048
#define TWO_I 1536
#define MAX_TILES 96   // sum ceil(cnt/128) <= 32 + 8192/128 = 96

typedef __attribute__((ext_vector_type(8))) short short8;
typedef __attribute__((ext_vector_type(4))) float floatx4;

// ws layout (bytes) — shared by both paths
#define WS_OFFSETS 0                       // int[33]
#define WS_IDS     1024                    // int[8192]
#define WS_WTS     (1024 + 32768)          // float[8192]
#define WS_TILES   (1024 + 65536)          // int[96]: (e<<16)|mtile, -1 = dead
#define WS_INTER   131072                  // bf16[8192*768]
#define WS_HID16   (131072 + 8192*768*2)   // bf16[2048*2048]
// big-path extras: transposed bf16 weights
#define WS_GUPT    21102592ULL             // bf16[E][2I][H] = 201326592 B
#define WS_DOWNT   222429184ULL            // bf16[E][H][I]  = 100663296 B
#define WS_BIG_TOTAL 323092480ULL

__device__ __forceinline__ unsigned short f2bf(float f) {
  union { float f; unsigned u; } v; v.f = f;
  unsigned r = v.u + 0x7FFFu + ((v.u >> 16) & 1u);   // RNE
  return (unsigned short)(r >> 16);
}

__device__ __forceinline__ unsigned pkbf(float a, float b) {
  // packed fp32->bf16 RNE pair; lowers to v_cvt_pk_bf16_f32 when available
  __hip_bfloat162 h = __float22bfloat162_rn(float2{a, b});
  union { __hip_bfloat162 h; unsigned u; } v; v.h = h; return v.u;
}

// async global->LDS, 16B per lane; LDS dest = wave-uniform base + lane*16
__device__ __forceinline__ void gload_lds16(const unsigned short* g, unsigned short* l) {
  __builtin_amdgcn_global_load_lds(
      (__attribute__((address_space(1))) void*)g,
      (__attribute__((address_space(3))) void*)l, 16, 0, 0);
}

// ---- routing: group slots by expert (dedupe = numpy last-write-wins) + tile list ----
__global__ void build_routing(const int* __restrict__ idx, const float* __restrict__ w,
                              char* __restrict__ ws) {
  int* offs = (int*)(ws + WS_OFFSETS);
  int* ids  = (int*)(ws + WS_IDS);
  float* wt = (float*)(ws + WS_WTS);
  int* tiles = (int*)(ws + WS_TILES);
  __shared__ int s_cnt[E_];
  __shared__ int s_pos[E_];
  int tid = threadIdx.x;
  if (tid < E_) s_cnt[tid] = 0;
  __syncthreads();
  for (int i = tid; i < T_ * 4; i += 256) {
    int t = i >> 2, j = i & 3;
    int e = idx[i];
    bool keep = true;
    for (int j2 = j + 1; j2 < 4; ++j2) if (idx[t * 4 + j2] == e) keep = false;
    if (keep) atomicAdd(&s_cnt[e], 1);
  }
  __syncthreads();
  if (tid == 0) {
    int run = 0;
    for (int e = 0; e < E_; ++e) { offs[e] = run; s_pos[e] = run; run += s_cnt[e]; }
    offs[E_] = run;
    int nt = 0;
    for (int e = 0; e < E_; ++e)
      for (int m0 = 0; m0 < s_cnt[e]; m0 += 128) tiles[nt++] = (e << 16) | (m0 >> 7);
    for (; nt < MAX_TILES; ++nt) tiles[nt] = -1;
  }
  __syncthreads();
  for (int i = tid; i < T_ * 4; i += 256) {
    int t = i >> 2, j = i & 3;
    int e = idx[i];
    bool keep = true;
    for (int j2 = j + 1; j2 < 4; ++j2) if (idx[t * 4 + j2] == e) keep = false;
    if (keep) {
      int p = atomicAdd(&s_pos[e], 1);
      ids[p] = t;
      wt[p] = w[i];
    }
  }
}

// ---- hidden fp32 -> bf16 once ----
__global__ void cvt_hidden(const float* __restrict__ hs, char* __restrict__ ws) {
  int g = blockIdx.x * 256 + threadIdx.x;            // 524288 threads, 8 elem each
  const float4 f0 = ((const float4*)hs)[g * 2];
  const float4 f1 = ((const float4*)hs)[g * 2 + 1];
  uint4 o;
  o.x = pkbf(f0.x, f0.y); o.y = pkbf(f0.z, f0.w);
  o.z = pkbf(f1.x, f1.y); o.w = pkbf(f1.z, f1.w);
  ((uint4*)(ws + WS_HID16))[g] = o;
}

// ---- transpose-convert: per expert, in fp32 [R][C] -> out bf16 [C][R] ----
template<int R, int C>
__global__ void tconv(const float* __restrict__ in, unsigned short* __restrict__ outp) {
  __shared__ float tile[64][65];
  int e = blockIdx.z;
  int rb = blockIdx.y * 64, cb = blockIdx.x * 64;
  const float* src = in + (size_t)e * R * C;
  unsigned short* dst = outp + (size_t)e * R * C;
  int t = threadIdx.x;
  int tr = t >> 4, tc4 = t & 15;
#pragma unroll
  for (int p = 0; p < 4; ++p) {
    int r = p * 16 + tr;
    const float4 v = *(const float4*)(src + (size_t)(rb + r) * C + cb + tc4 * 4);
    tile[r][tc4 * 4 + 0] = v.x;
    tile[r][tc4 * 4 + 1] = v.y;
    tile[r][tc4 * 4 + 2] = v.z;
    tile[r][tc4 * 4 + 3] = v.w;
  }
  __syncthreads();
  int c0 = t >> 3, r0 = (t & 7) * 8;
#pragma unroll
  for (int q = 0; q < 2; ++q) {
    int c = q * 32 + c0;
    uint4 o;
    o.x = pkbf(tile[r0 + 0][c], tile[r0 + 1][c]);
    o.y = pkbf(tile[r0 + 2][c], tile[r0 + 3][c]);
    o.z = pkbf(tile[r0 + 4][c], tile[r0 + 5][c]);
    o.w = pkbf(tile[r0 + 6][c], tile[r0 + 7][c]);
    *(uint4*)(dst + (size_t)(cb + c) * R + rb + r0) = o;
  }
}

// ======================= big path: bf16 B^T GEMMs (m97 structure) =======================
// LDS tiles [128][64] bf16, linear (global_load_lds), 16B-granule XOR swizzle:
// slot (r, cs) holds logical (r, cs ^ (r&7)); read logical (r,c) at cs = c ^ (r&7).

// GEMM1: gathered hid16 [cnt,2048] x gupT[e][1536,2048]^T-panel, fused silu*up
__global__ __launch_bounds__(256, 3) void gemm1_bf(char* __restrict__ ws) {
  const int* offs = (const int*)(ws + WS_OFFSETS);
  const int* ids  = (const int*)(ws + WS_IDS);
  const int* tiles = (const int*)(ws + WS_TILES);
  const unsigned short* h16  = (const unsigned short*)(ws + WS_HID16);
  const unsigned short* gupT = (const unsigned short*)(ws + WS_GUPT);
  unsigned short* inter = (unsigned short*)(ws + WS_INTER);

  int tl = tiles[blockIdx.y];
  if (tl < 0) return;
  int e = tl >> 16, m0 = (tl & 0xffff) << 7;
  int start = offs[e];
  int mrem = offs[e + 1] - start - m0;
  int n0 = blockIdx.x * 64;

  __shared__ __align__(16) unsigned short Al[128 * 64];
  __shared__ __align__(16) unsigned short Bl[128 * 64];

  int tid = threadIdx.x, lane = tid & 63, w = tid >> 6;
  int wy = w >> 1, wx = w & 1, quad = lane >> 4, l15 = lane & 15;

  // per-lane staging sources (loop-invariant); inverse-swizzled k-offset
  const unsigned short* aSrc[4];
  const unsigned short* bSrc[4];
#pragma unroll
  for (int u = 0; u < 4; ++u) {
    int s = (w * 4 + u) * 64 + lane;          // linear 16B slot 0..1023
    int r = s >> 3;
    int c = (s & 7) ^ (r & 7);
    int tok = ids[start + m0 + ((r < mrem) ? r : 0)];
    aSrc[u] = h16 + (size_t)tok * H_ + c * 8;
    int grow = (r < 64) ? (n0 + r) : (I_ + n0 + (r - 64));   // 64 gate + 64 up rows
    bSrc[u] = gupT + ((size_t)e * TWO_I + grow) * H_ + c * 8;
  }

  floatx4 acc[4][4] = {};

  for (int kb = 0; kb < H_ / 64; ++kb) {
#pragma unroll
    for (int u = 0; u < 4; ++u) {
      gload_lds16(aSrc[u] + kb * 64, &Al[(w * 4 + u) * 512]);
      gload_lds16(bSrc[u] + kb * 64, &Bl[(w * 4 + u) * 512]);
    }
    __syncthreads();   // compiler drains vmcnt before s_barrier -> LDS visible
#pragma unroll
    for (int ks = 0; ks < 2; ++ks) {
      short8 af[4], bfr[4];
#pragma unroll
      for (int mi = 0; mi < 4; ++mi) {
        int row = wy * 64 + mi * 16 + l15;
        int c16 = (ks * 4 + quad) ^ (row & 7);
        af[mi] = *(const short8*)&Al[row * 64 + c16 * 8];
      }
#pragma unroll
      for (int ni = 0; ni < 4; ++ni) {
        int j = (ni < 2) ? (wx * 32 + ni * 16 + l15) : (64 + wx * 32 + (ni - 2) * 16 + l15);
        int c16 = (ks * 4 + quad) ^ (j & 7);
        bfr[ni] = *(const short8*)&Bl[j * 64 + c16 * 8];
      }
#pragma unroll
      for (int mi = 0; mi < 4; ++mi)
#pragma unroll
        for (int ni = 0; ni < 4; ++ni)
          acc[mi][ni] = __builtin_amdgcn_mfma_f32_16x16x32_bf16(af[mi], bfr[ni], acc[mi][ni], 0, 0, 0);
    }
    __syncthreads();
  }

  // epilogue: inter = silu(gate) * up
#pragma unroll
  for (int mi = 0; mi < 4; ++mi) {
#pragma unroll
    for (int r = 0; r < 4; ++r) {
      int row = wy * 64 + mi * 16 + quad * 4 + r;
      if (row < mrem) {
        int slot = start + m0 + row;
#pragma unroll
        for (int ni = 0; ni < 2; ++ni) {
          float g = acc[mi][ni][r];
          float u = acc[mi][ni + 2][r];
          float s = g / (1.f + __expf(-g));
          int col = n0 + wx * 32 + ni * 16 + l15;
          inter[(size_t)slot * I_ + col] = f2bf(s * u);
        }
      }
    }
  }
}

// GEMM2: inter [cnt,768] x downT[e][2048,768]; weighted atomicAdd
__global__ __launch_bounds__(256, 3) void gemm2_bf(float* __restrict__ out, char* __restrict__ ws) {
  const int* offs = (const int*)(ws + WS_OFFSETS);
  const int* ids  = (const int*)(ws + WS_IDS);
  const float* wt = (const float*)(ws + WS_WTS);
  const int* tiles = (const int*)(ws + WS_TILES);
  const unsigned short* inter = (const unsigned short*)(ws + WS_INTER);
  const unsigned short* downT = (const unsigned short*)(ws + WS_DOWNT);

  int tl = tiles[blockIdx.y];
  if (tl < 0) return;
  int e = tl >> 16, m0 = (tl & 0xffff) << 7;
  int start = offs[e];
  int mrem = offs[e + 1] - start - m0;
  int n0 = blockIdx.x * 128;

  __shared__ __align__(16) unsigned short Al[128 * 64];
  __shared__ __align__(16) unsigned short Bl[128 * 64];

  int tid = threadIdx.x, lane = tid & 63, w = tid >> 6;
  int wy = w >> 1, wx = w & 1, quad = lane >> 4, l15 = lane & 15;

  const unsigned short* aSrc[4];
  const unsigned short* bSrc[4];
#pragma unroll
  for (int u = 0; u < 4; ++u) {
    int s = (w * 4 + u) * 64 + lane;
    int r = s >> 3;
    int c = (s & 7) ^ (r & 7);
    int arow = (r < mrem) ? r : 0;
    aSrc[u] = inter + (size_t)(start + m0 + arow) * I_ + c * 8;
    bSrc[u] = downT + ((size_t)e * H_ + (n0 + r)) * I_ + c * 8;
  }

  floatx4 acc[4][4] = {};

  for (int kb = 0; kb < I_ / 64; ++kb) {
#pragma unroll
    for (int u = 0; u < 4; ++u) {
      gload_lds16(aSrc[u] + kb * 64, &Al[(w * 4 + u) * 512]);
      gload_lds16(bSrc[u] + kb * 64, &Bl[(w * 4 + u) * 512]);
    }
    __syncthreads();
#pragma unroll
    for (int ks = 0; ks < 2; ++ks) {
      short8 af[4], bfr[4];
#pragma unroll
      for (int mi = 0; mi < 4; ++mi) {
        int row = wy * 64 + mi * 16 + l15;
        int c16 = (ks * 4 + quad) ^ (row & 7);
        af[mi] = *(const short8*)&Al[row * 64 + c16 * 8];
      }
#pragma unroll
      for (int ni = 0; ni < 4; ++ni) {
        int j = wx * 64 + ni * 16 + l15;
        int c16 = (ks * 4 + quad) ^ (j & 7);
        bfr[ni] = *(const short8*)&Bl[j * 64 + c16 * 8];
      }
#pragma unroll
      for (int mi = 0; mi < 4; ++mi)
#pragma unroll
        for (int ni = 0; ni < 4; ++ni)
          acc[mi][ni] = __builtin_amdgcn_mfma_f32_16x16x32_bf16(af[mi], bfr[ni], acc[mi][ni], 0, 0, 0);
    }
    __syncthreads();
  }

#pragma unroll
  for (int mi = 0; mi < 4; ++mi) {
#pragma unroll
    for (int r = 0; r < 4; ++r) {
      int row = wy * 64 + mi * 16 + quad * 4 + r;
      if (row < mrem) {
        int slot = start + m0 + row;
        int t = ids[slot];
        float wv = wt[slot];
#pragma unroll
        for (int ni = 0; ni < 4; ++ni) {
          int col = n0 + wx * 64 + ni * 16 + l15;
          atomicAdd(out + (size_t)t * H_ + col, wv * acc[mi][ni][r]);
        }
      }
    }
  }
}

// ======================= fallback path (verified baseline, fp32 weights) =======================
__global__ __launch_bounds__(256, 2) void gemm1_fb(
    const float* __restrict__ gup, char* __restrict__ ws) {
  const int* offs = (const int*)(ws + WS_OFFSETS);
  const int* ids  = (const int*)(ws + WS_IDS);
  const int* tiles = (const int*)(ws + WS_TILES);
  const unsigned short* h16 = (const unsigned short*)(ws + WS_HID16);
  unsigned short* inter = (unsigned short*)(ws + WS_INTER);

  int tl = tiles[blockIdx.y];
  if (tl < 0) return;
  int e = tl >> 16, m0 = (tl & 0xffff) << 7;
  int start = offs[e];
  int mrem = offs[e + 1] - start - m0;
  int n0 = blockIdx.x * 64;

  __shared__ __align__(16) unsigned short Al[128][72];
  __shared__ __align__(16) unsigned short Bl[128][72];

  int tid = threadIdx.x, lane = tid & 63, wid = tid >> 6;
  int wy = wid >> 1, wx = wid & 1, quad = lane >> 4, l15 = lane & 15;

  floatx4 acc[4][4] = {};

  int arow[4], ako[4];
  const unsigned short* asrc[4];
#pragma unroll
  for (int u = 0; u < 4; ++u) {
    int lin = tid + u * 256;
    arow[u] = lin >> 3; ako[u] = (lin & 7) * 8;
    int tok = (arow[u] < mrem) ? ids[start + m0 + arow[u]] : -1;
    asrc[u] = (tok >= 0) ? h16 + (size_t)tok * H_ + ako[u] : nullptr;
  }
  int bj = tid & 127;
  int kr0 = (tid >> 7) * 32;
  int gc = (bj < 64) ? (n0 + bj) : (I_ + n0 + (bj - 64));
  const float* gbase = gup + (size_t)e * H_ * TWO_I + gc;

  uint4 pf_a[4];
  float pf_b[32];

  auto loadA = [&](int kb) {
#pragma unroll
    for (int u = 0; u < 4; ++u)
      pf_a[u] = asrc[u] ? *(const uint4*)(asrc[u] + (size_t)kb * 64) : uint4{0u, 0u, 0u, 0u};
  };
  auto loadB = [&](int kb) {
    const float* p = gbase + (size_t)(kb * 64 + kr0) * TWO_I;
#pragma unroll
    for (int r = 0; r < 32; ++r) pf_b[r] = p[(size_t)r * TWO_I];
  };

  loadA(0); loadB(0);
  for (int kb = 0; kb < H_ / 64; ++kb) {
#pragma unroll
    for (int u = 0; u < 4; ++u) *(uint4*)&Al[arow[u]][ako[u]] = pf_a[u];
#pragma unroll
    for (int q = 0; q < 4; ++q) {
      uint4 wv;
      wv.x = pkbf(pf_b[q * 8 + 0], pf_b[q * 8 + 1]);
      wv.y = pkbf(pf_b[q * 8 + 2], pf_b[q * 8 + 3]);
      wv.z = pkbf(pf_b[q * 8 + 4], pf_b[q * 8 + 5]);
      wv.w = pkbf(pf_b[q * 8 + 6], pf_b[q * 8 + 7]);
      *(uint4*)&Bl[bj][kr0 + q * 8] = wv;
    }
    __syncthreads();
    if (kb + 1 < H_ / 64) { loadA(kb + 1); loadB(kb + 1); }
#pragma unroll
    for (int ks = 0; ks < 2; ++ks) {
      short8 af[4], bfr[4];
#pragma unroll
      for (int mi = 0; mi < 4; ++mi)
        af[mi] = *(const short8*)&Al[wy * 64 + mi * 16 + l15][ks * 32 + quad * 8];
#pragma unroll
      for (int ni = 0; ni < 4; ++ni) {
        int j = (ni < 2) ? (wx * 32 + ni * 16 + l15) : (64 + wx * 32 + (ni - 2) * 16 + l15);
        bfr[ni] = *(const short8*)&Bl[j][ks * 32 + quad * 8];
      }
#pragma unroll
      for (int mi = 0; mi < 4; ++mi)
#pragma unroll
        for (int ni = 0; ni < 4; ++ni)
          acc[mi][ni] = __builtin_amdgcn_mfma_f32_16x16x32_bf16(af[mi], bfr[ni], acc[mi][ni], 0, 0, 0);
    }
    __syncthreads();
  }

#pragma unroll
  for (int mi = 0; mi < 4; ++mi) {
#pragma unroll
    for (int r = 0; r < 4; ++r) {
      int row = wy * 64 + mi * 16 + quad * 4 + r;
      if (row < mrem) {
        int slot = start + m0 + row;
#pragma unroll
        for (int ni = 0; ni < 2; ++ni) {
          float g = acc[mi][ni][r];
          float u = acc[mi][ni + 2][r];
          float s = g / (1.f + __expf(-g));
          int col = n0 + wx * 32 + ni * 16 + l15;
          inter[(size_t)slot * I_ + col] = f2bf(s * u);
        }
      }
    }
  }
}

__global__ __launch_bounds__(256, 2) void gemm2_fb(
    const float* __restrict__ down, float* __restrict__ out, char* __restrict__ ws) {
  const int* offs = (const int*)(ws + WS_OFFSETS);
  const int* ids  = (const int*)(ws + WS_IDS);
  const float* wt = (const float*)(ws + WS_WTS);
  const int* tiles = (const int*)(ws + WS_TILES);
  const unsigned short* inter = (const unsigned short*)(ws + WS_INTER);

  int tl = tiles[blockIdx.y];
  if (tl < 0) return;
  int e = tl >> 16, m0 = (tl & 0xffff) << 7;
  int start = offs[e];
  int mrem = offs[e + 1] - start - m0;
  int n0 = blockIdx.x * 128;

  __shared__ __align__(16) unsigned short Al[128][72];
  __shared__ __align__(16) unsigned short Bl[128][72];

  int tid = threadIdx.x, lane = tid & 63, wid = tid >> 6;
  int wy = wid >> 1, wx = wid & 1, quad = lane >> 4, l15 = lane & 15;

  floatx4 acc[4][4] = {};

  int arow[4], ako[4];
  const unsigned short* asrc[4];
#pragma unroll
  for (int u = 0; u < 4; ++u) {
    int lin = tid + u * 256;
    arow[u] = lin >> 3; ako[u] = (lin & 7) * 8;
    asrc[u] = (arow[u] < mrem) ? inter + (size_t)(start + m0 + arow[u]) * I_ + ako[u] : nullptr;
  }
  int bj = tid & 127;
  int kr0 = (tid >> 7) * 32;
  const float* dbase = down + (size_t)e * I_ * H_ + (n0 + bj);

  uint4 pf_a[4];
  float pf_b[32];

  auto loadA = [&](int kb) {
#pragma unroll
    for (int u = 0; u < 4; ++u)
      pf_a[u] = asrc[u] ? *(const uint4*)(asrc[u] + (size_t)kb * 64) : uint4{0u, 0u, 0u, 0u};
  };
  auto loadB = [&](int kb) {
    const float* p = dbase + (size_t)(kb * 64 + kr0) * H_;
#pragma unroll
    for (int r = 0; r < 32; ++r) pf_b[r] = p[(size_t)r * H_];
  };

  loadA(0); loadB(0);
  for (int kb = 0; kb < I_ / 64; ++kb) {
#pragma unroll
    for (int u = 0; u < 4; ++u) *(uint4*)&Al[arow[u]][ako[u]] = pf_a[u];
#pragma unroll
    for (int q = 0; q < 4; ++q) {
      uint4 wv;
      wv.x = pkbf(pf_b[q * 8 + 0], pf_b[q * 8 + 1]);
      wv.y = pkbf(pf_b[q * 8 + 2], pf_b[q * 8 + 3]);
      wv.z = pkbf(pf_b[q * 8 + 4], pf_b[q * 8 + 5]);
      wv.w = pkbf(pf_b[q * 8 + 6], pf_b[q * 8 + 7]);
      *(uint4*)&Bl[bj][kr0 + q * 8] = wv;
    }
    __syncthreads();
    if (kb + 1 < I_ / 64) { loadA(kb + 1); loadB(kb + 1); }
#pragma unroll
    for (int ks = 0; ks < 2; ++ks) {
      short8 af[4], bfr[4];
#pragma unroll
      for (int mi = 0; mi < 4; ++mi)
        af[mi] = *(const short8*)&Al[wy * 64 + mi * 16 + l15][ks * 32 + quad * 8];
#pragma unroll
      for (int ni = 0; ni < 4; ++ni)
        bfr[ni] = *(const short8*)&Bl[wx * 64 + ni * 16 + l15][ks * 32 + quad * 8];
#pragma unroll
      for (int mi = 0; mi < 4; ++mi)
#pragma unroll
        for (int ni = 0; ni < 4; ++ni)
          acc[mi][ni] = __builtin_amdgcn_mfma_f32_16x16x32_bf16(af[mi], bfr[ni], acc[mi][ni], 0, 0, 0);
    }
    __syncthreads();
  }

#pragma unroll
  for (int mi = 0; mi < 4; ++mi) {
#pragma unroll
    for (int r = 0; r < 4; ++r) {
      int row = wy * 64 + mi * 16 + quad * 4 + r;
      if (row < mrem) {
        int slot = start + m0 + row;
        int t = ids[slot];
        float w = wt[slot];
#pragma unroll
        for (int ni = 0; ni < 4; ++ni) {
          int col = n0 + wx * 64 + ni * 16 + l15;
          atomicAdd(out + (size_t)t * H_ + col, w * acc[mi][ni][r]);
        }
      }
    }
  }
}

extern "C" void kernel_launch(void* const* d_in, const int* in_sizes, int n_in,
                              void* d_out, int out_size, void* d_ws, size_t ws_size,
                              hipStream_t stream) {
  (void)in_sizes; (void)n_in; (void)out_size;
  const float* hidden = (const float*)d_in[0];
  const int* idx      = (const int*)d_in[1];
  const float* w      = (const float*)d_in[2];
  const float* gup    = (const float*)d_in[3];
  const float* down   = (const float*)d_in[4];
  float* out = (float*)d_out;
  char* ws = (char*)d_ws;

  hipMemsetAsync(d_out, 0, (size_t)T_ * H_ * sizeof(float), stream);
  build_routing<<<1, 256, 0, stream>>>(idx, w, ws);
  cvt_hidden<<<T_ * H_ / 8 / 256, 256, 0, stream>>>(hidden, ws);

  if (ws_size >= WS_BIG_TOTAL) {
    unsigned short* gupT  = (unsigned short*)(ws + WS_GUPT);
    unsigned short* downT = (unsigned short*)(ws + WS_DOWNT);
    // gup [E][2048][1536] -> gupT [E][1536][2048]
    tconv<2048, 1536><<<dim3(1536 / 64, 2048 / 64, E_), 256, 0, stream>>>(gup, gupT);
    // down [E][768][2048] -> downT [E][2048][768]
    tconv<768, 2048><<<dim3(2048 / 64, 768 / 64, E_), 256, 0, stream>>>(down, downT);
    gemm1_bf<<<dim3(I_ / 64, MAX_TILES), 256, 0, stream>>>(ws);
    gemm2_bf<<<dim3(H_ / 128, MAX_TILES), 256, 0, stream>>>(out, ws);
  } else {
    gemm1_fb<<<dim3(I_ / 64, MAX_TILES), 256, 0, stream>>>(gup, ws);
    gemm2_fb<<<dim3(H_ / 128, MAX_TILES), 256, 0, stream>>>(down, out, ws);
  }
}

// Round 2
// 799.581 us; speedup vs baseline: 1.1598x; 1.1598x over previous
//
#include <hip/hip_runtime.h>
#include <hip/hip_bf16.h>

// Qwen3VLMoeTextExpertsTransposed: E=32,H=2048,I=768,K=4,T=2048
#define E_ 32
#define H_ 2048
#define I_ 768
#define T_ 2048
#define TWO_I 1536
#define MAX_TILES 96   // sum ceil(cnt/128) <= 32 + 8192/128 = 96

typedef __attribute__((ext_vector_type(8))) short short8;
typedef __attribute__((ext_vector_type(4))) float floatx4;

// ws layout (bytes)
#define WS_OFFSETS 0                       // int[33]
#define WS_IDS     1024                    // int[8192]
#define WS_WTS     (1024 + 32768)          // float[8192]
#define WS_TILES   (1024 + 65536)          // int[96]: (e<<16)|mtile, -1 = dead
#define WS_SLOTTJ  69632                   // int[8192]: slot of (t,j) or -1
#define WS_INTER   131072                  // bf16[8192*768]
#define WS_HID16   (131072 + 8192*768*2)   // bf16[2048*2048]
#define WS_EO      21102592ULL             // fp32[8192*2048] weighted expert outs (67 MB)

__device__ __forceinline__ unsigned short f2bf(float f) {
  union { float f; unsigned u; } v; v.f = f;
  unsigned r = v.u + 0x7FFFu + ((v.u >> 16) & 1u);   // RNE
  return (unsigned short)(r >> 16);
}

__device__ __forceinline__ unsigned pkbf(float a, float b) {
  // packed fp32->bf16 RNE pair; lowers to v_cvt_pk_bf16_f32 when available
  __hip_bfloat162 h = __float22bfloat162_rn(float2{a, b});
  union { __hip_bfloat162 h; unsigned u; } v; v.h = h; return v.u;
}

// ---- routing: group slots by expert (dedupe = numpy last-write-wins) + tile list ----
__global__ void build_routing(const int* __restrict__ idx, const float* __restrict__ w,
                              char* __restrict__ ws) {
  int* offs = (int*)(ws + WS_OFFSETS);
  int* ids  = (int*)(ws + WS_IDS);
  float* wt = (float*)(ws + WS_WTS);
  int* tiles = (int*)(ws + WS_TILES);
  int* slot_tj = (int*)(ws + WS_SLOTTJ);
  __shared__ int s_cnt[E_];
  __shared__ int s_pos[E_];
  int tid = threadIdx.x;
  if (tid < E_) s_cnt[tid] = 0;
  __syncthreads();
  for (int i = tid; i < T_ * 4; i += 256) {
    int t = i >> 2, j = i & 3;
    int e = idx[i];
    bool keep = true;
    for (int j2 = j + 1; j2 < 4; ++j2) if (idx[t * 4 + j2] == e) keep = false;
    if (keep) atomicAdd(&s_cnt[e], 1);
  }
  __syncthreads();
  if (tid == 0) {
    int run = 0;
    for (int e = 0; e < E_; ++e) { offs[e] = run; s_pos[e] = run; run += s_cnt[e]; }
    offs[E_] = run;
    int nt = 0;
    for (int e = 0; e < E_; ++e)
      for (int m0 = 0; m0 < s_cnt[e]; m0 += 128) tiles[nt++] = (e << 16) | (m0 >> 7);
    for (; nt < MAX_TILES; ++nt) tiles[nt] = -1;
  }
  __syncthreads();
  for (int i = tid; i < T_ * 4; i += 256) {
    int t = i >> 2, j = i & 3;
    int e = idx[i];
    bool keep = true;
    for (int j2 = j + 1; j2 < 4; ++j2) if (idx[t * 4 + j2] == e) keep = false;
    if (keep) {
      int p = atomicAdd(&s_pos[e], 1);
      ids[p] = t;
      wt[p] = w[i];
      slot_tj[i] = p;
    } else {
      slot_tj[i] = -1;
    }
  }
}

// ---- hidden fp32 -> bf16 once ----
__global__ void cvt_hidden(const float* __restrict__ hs, char* __restrict__ ws) {
  int g = blockIdx.x * 256 + threadIdx.x;            // 524288 threads, 8 elem each
  const float4 f0 = ((const float4*)hs)[g * 2];
  const float4 f1 = ((const float4*)hs)[g * 2 + 1];
  uint4 o;
  o.x = pkbf(f0.x, f0.y); o.y = pkbf(f0.z, f0.w);
  o.z = pkbf(f1.x, f1.y); o.w = pkbf(f1.z, f1.w);
  ((uint4*)(ws + WS_HID16))[g] = o;
}

// ===== GEMM1: gathered hid16 [cnt,2048] x gate_up[e][2048,1536], fused silu*up =====
// BM=128, BK=64. B staged via 8x float4 (k-pair scheme) + packed cvt + XOR-swizzled
// transposed ds_write_b32. Bl logical layout [col 0..127][k 0..63] bf16, pitch 72;
// 16B chunk c of row r stored at chunk c ^ ((r>>2)&7).
__global__ __launch_bounds__(256, 2) void gemm1(
    const float* __restrict__ gup, char* __restrict__ ws) {
  const int* offs = (const int*)(ws + WS_OFFSETS);
  const int* ids  = (const int*)(ws + WS_IDS);
  const int* tiles = (const int*)(ws + WS_TILES);
  const unsigned short* h16 = (const unsigned short*)(ws + WS_HID16);
  unsigned short* inter = (unsigned short*)(ws + WS_INTER);

  int tl = tiles[blockIdx.y];
  if (tl < 0) return;
  int e = tl >> 16, m0 = (tl & 0xffff) << 7;
  int start = offs[e];
  int mrem = offs[e + 1] - start - m0;
  int n0 = blockIdx.x * 64;

  __shared__ __align__(16) unsigned short Al[128][72];
  __shared__ __align__(16) unsigned short Bl[128][72];

  int tid = threadIdx.x, lane = tid & 63, wid = tid >> 6;
  int wy = wid >> 1, wx = wid & 1, quad = lane >> 4, l15 = lane & 15;

  floatx4 acc[4][4] = {};

  // A map: 4 units/thread, unit = 8 contiguous k of one row
  int arow[4], ako[4];
  const unsigned short* asrc[4];
#pragma unroll
  for (int u = 0; u < 4; ++u) {
    int lin = tid + u * 256;
    arow[u] = lin >> 3; ako[u] = (lin & 7) * 8;
    int tok = (arow[u] < mrem) ? ids[start + m0 + arow[u]] : -1;
    asrc[u] = (tok >= 0) ? h16 + (size_t)tok * H_ + ako[u] : nullptr;
  }
  // B map: 4 k-pair units/thread. unit pp: lin2 = tid + 256*pp (0..1023);
  // k2 = lin2>>5 (k-pair 0..31), c4 = lin2&31 (4-col group; <16 gate, >=16 up).
  const float* gB[4];
  int brow0[4], bofs[4];
#pragma unroll
  for (int pp = 0; pp < 4; ++pp) {
    int lin2 = tid + 256 * pp;
    int k2 = lin2 >> 5, c4 = lin2 & 31;
    int gcol = (c4 < 16) ? (n0 + c4 * 4) : (I_ + n0 + (c4 - 16) * 4);
    gB[pp] = gup + (size_t)e * H_ * TWO_I + (size_t)(2 * k2) * TWO_I + gcol;
    brow0[pp] = c4 * 4;                                   // LDS row base (0..124)
    int chunkp = (k2 >> 2) ^ (c4 & 7);                    // stored chunk (XOR swizzle)
    bofs[pp] = chunkp * 8 + (k2 & 3) * 2;                 // short offset within row
  }

  uint4 pf_a[4];
  float4 pf0[4], pf1[4];

  auto loadA = [&](int kb) {
#pragma unroll
    for (int u = 0; u < 4; ++u)
      pf_a[u] = asrc[u] ? *(const uint4*)(asrc[u] + (size_t)kb * 64) : uint4{0u, 0u, 0u, 0u};
  };
  auto loadB = [&](int kb) {
#pragma unroll
    for (int pp = 0; pp < 4; ++pp) {
      const float* p = gB[pp] + (size_t)kb * 64 * TWO_I;
      pf0[pp] = *(const float4*)p;
      pf1[pp] = *(const float4*)(p + TWO_I);
    }
  };

  loadA(0); loadB(0);
  for (int kb = 0; kb < H_ / 64; ++kb) {
#pragma unroll
    for (int u = 0; u < 4; ++u) *(uint4*)&Al[arow[u]][ako[u]] = pf_a[u];
#pragma unroll
    for (int pp = 0; pp < 4; ++pp) {
      *(unsigned*)&Bl[brow0[pp] + 0][bofs[pp]] = pkbf(pf0[pp].x, pf1[pp].x);
      *(unsigned*)&Bl[brow0[pp] + 1][bofs[pp]] = pkbf(pf0[pp].y, pf1[pp].y);
      *(unsigned*)&Bl[brow0[pp] + 2][bofs[pp]] = pkbf(pf0[pp].z, pf1[pp].z);
      *(unsigned*)&Bl[brow0[pp] + 3][bofs[pp]] = pkbf(pf0[pp].w, pf1[pp].w);
    }
    __syncthreads();
    if (kb + 1 < H_ / 64) { loadA(kb + 1); loadB(kb + 1); }  // prefetch under compute
#pragma unroll
    for (int ks = 0; ks < 2; ++ks) {
      short8 af[4], bfr[4];
#pragma unroll
      for (int mi = 0; mi < 4; ++mi)
        af[mi] = *(const short8*)&Al[wy * 64 + mi * 16 + l15][ks * 32 + quad * 8];
#pragma unroll
      for (int ni = 0; ni < 4; ++ni) {
        int j = (ni < 2) ? (wx * 32 + ni * 16 + l15) : (64 + wx * 32 + (ni - 2) * 16 + l15);
        int ch = (ks * 4 + quad) ^ ((j >> 2) & 7);
        bfr[ni] = *(const short8*)&Bl[j][ch * 8];
      }
#pragma unroll
      for (int mi = 0; mi < 4; ++mi)
#pragma unroll
        for (int ni = 0; ni < 4; ++ni)
          acc[mi][ni] = __builtin_amdgcn_mfma_f32_16x16x32_bf16(af[mi], bfr[ni], acc[mi][ni], 0, 0, 0);
    }
    __syncthreads();
  }

  // epilogue: inter = silu(gate) * up
#pragma unroll
  for (int mi = 0; mi < 4; ++mi) {
#pragma unroll
    for (int r = 0; r < 4; ++r) {
      int row = wy * 64 + mi * 16 + quad * 4 + r;
      if (row < mrem) {
        int slot = start + m0 + row;
#pragma unroll
        for (int ni = 0; ni < 2; ++ni) {
          float g = acc[mi][ni][r];
          float u = acc[mi][ni + 2][r];
          float s = g / (1.f + __expf(-g));
          int col = n0 + wx * 32 + ni * 16 + l15;
          inter[(size_t)slot * I_ + col] = f2bf(s * u);
        }
      }
    }
  }
}

// ===== GEMM2: inter [cnt,768] x down[e][768,2048]; weighted store to eo (no atomics) =====
__global__ __launch_bounds__(256, 2) void gemm2(
    const float* __restrict__ down, char* __restrict__ ws) {
  const int* offs = (const int*)(ws + WS_OFFSETS);
  const float* wt = (const float*)(ws + WS_WTS);
  const int* tiles = (const int*)(ws + WS_TILES);
  const unsigned short* inter = (const unsigned short*)(ws + WS_INTER);
  float* eo = (float*)(ws + WS_EO);

  int tl = tiles[blockIdx.y];
  if (tl < 0) return;
  int e = tl >> 16, m0 = (tl & 0xffff) << 7;
  int start = offs[e];
  int mrem = offs[e + 1] - start - m0;
  int n0 = blockIdx.x * 128;

  __shared__ __align__(16) unsigned short Al[128][72];
  __shared__ __align__(16) unsigned short Bl[128][72];

  int tid = threadIdx.x, lane = tid & 63, wid = tid >> 6;
  int wy = wid >> 1, wx = wid & 1, quad = lane >> 4, l15 = lane & 15;

  floatx4 acc[4][4] = {};

  int arow[4], ako[4];
  const unsigned short* asrc[4];
#pragma unroll
  for (int u = 0; u < 4; ++u) {
    int lin = tid + u * 256;
    arow[u] = lin >> 3; ako[u] = (lin & 7) * 8;
    asrc[u] = (arow[u] < mrem) ? inter + (size_t)(start + m0 + arow[u]) * I_ + ako[u] : nullptr;
  }
  // B map: k-pair units over [64k][128n] fp32
  const float* gB[4];
  int brow0[4], bofs[4];
#pragma unroll
  for (int pp = 0; pp < 4; ++pp) {
    int lin2 = tid + 256 * pp;
    int k2 = lin2 >> 5, c4 = lin2 & 31;
    gB[pp] = down + (size_t)e * I_ * H_ + (size_t)(2 * k2) * H_ + (n0 + c4 * 4);
    brow0[pp] = c4 * 4;
    int chunkp = (k2 >> 2) ^ (c4 & 7);
    bofs[pp] = chunkp * 8 + (k2 & 3) * 2;
  }

  uint4 pf_a[4];
  float4 pf0[4], pf1[4];

  auto loadA = [&](int kb) {
#pragma unroll
    for (int u = 0; u < 4; ++u)
      pf_a[u] = asrc[u] ? *(const uint4*)(asrc[u] + (size_t)kb * 64) : uint4{0u, 0u, 0u, 0u};
  };
  auto loadB = [&](int kb) {
#pragma unroll
    for (int pp = 0; pp < 4; ++pp) {
      const float* p = gB[pp] + (size_t)kb * 64 * H_;
      pf0[pp] = *(const float4*)p;
      pf1[pp] = *(const float4*)(p + H_);
    }
  };

  loadA(0); loadB(0);
  for (int kb = 0; kb < I_ / 64; ++kb) {
#pragma unroll
    for (int u = 0; u < 4; ++u) *(uint4*)&Al[arow[u]][ako[u]] = pf_a[u];
#pragma unroll
    for (int pp = 0; pp < 4; ++pp) {
      *(unsigned*)&Bl[brow0[pp] + 0][bofs[pp]] = pkbf(pf0[pp].x, pf1[pp].x);
      *(unsigned*)&Bl[brow0[pp] + 1][bofs[pp]] = pkbf(pf0[pp].y, pf1[pp].y);
      *(unsigned*)&Bl[brow0[pp] + 2][bofs[pp]] = pkbf(pf0[pp].z, pf1[pp].z);
      *(unsigned*)&Bl[brow0[pp] + 3][bofs[pp]] = pkbf(pf0[pp].w, pf1[pp].w);
    }
    __syncthreads();
    if (kb + 1 < I_ / 64) { loadA(kb + 1); loadB(kb + 1); }
#pragma unroll
    for (int ks = 0; ks < 2; ++ks) {
      short8 af[4], bfr[4];
#pragma unroll
      for (int mi = 0; mi < 4; ++mi)
        af[mi] = *(const short8*)&Al[wy * 64 + mi * 16 + l15][ks * 32 + quad * 8];
#pragma unroll
      for (int ni = 0; ni < 4; ++ni) {
        int j = wx * 64 + ni * 16 + l15;
        int ch = (ks * 4 + quad) ^ ((j >> 2) & 7);
        bfr[ni] = *(const short8*)&Bl[j][ch * 8];
      }
#pragma unroll
      for (int mi = 0; mi < 4; ++mi)
#pragma unroll
        for (int ni = 0; ni < 4; ++ni)
          acc[mi][ni] = __builtin_amdgcn_mfma_f32_16x16x32_bf16(af[mi], bfr[ni], acc[mi][ni], 0, 0, 0);
    }
    __syncthreads();
  }

#pragma unroll
  for (int mi = 0; mi < 4; ++mi) {
#pragma unroll
    for (int r = 0; r < 4; ++r) {
      int row = wy * 64 + mi * 16 + quad * 4 + r;
      if (row < mrem) {
        int slot = start + m0 + row;
        float wv = wt[slot];
#pragma unroll
        for (int ni = 0; ni < 4; ++ni) {
          int col = n0 + wx * 64 + ni * 16 + l15;
          eo[(size_t)slot * H_ + col] = wv * acc[mi][ni][r];
        }
      }
    }
  }
}

// ---- combine: out[t] = sum over valid slots of eo[slot] (weights folded in gemm2) ----
__global__ void combine(float* __restrict__ out, const char* __restrict__ ws) {
  const int* slot_tj = (const int*)(ws + WS_SLOTTJ);
  const float* eo = (const float*)(ws + WS_EO);
  int g = blockIdx.x * 256 + threadIdx.x;     // T*H/4 = 1048576 threads
  int token = g >> 9, c4 = g & 511;
  const int* st = slot_tj + token * 4;
  float4 s = {0.f, 0.f, 0.f, 0.f};
#pragma unroll
  for (int j = 0; j < 4; ++j) {
    int p = st[j];
    if (p >= 0) {
      const float4 v = *(const float4*)(eo + (size_t)p * H_ + c4 * 4);
      s.x += v.x; s.y += v.y; s.z += v.z; s.w += v.w;
    }
  }
  *(float4*)(out + (size_t)token * H_ + c4 * 4) = s;
}

extern "C" void kernel_launch(void* const* d_in, const int* in_sizes, int n_in,
                              void* d_out, int out_size, void* d_ws, size_t ws_size,
                              hipStream_t stream) {
  (void)in_sizes; (void)n_in; (void)out_size; (void)ws_size;
  const float* hidden = (const float*)d_in[0];
  const int* idx      = (const int*)d_in[1];
  const float* w      = (const float*)d_in[2];
  const float* gup    = (const float*)d_in[3];
  const float* down   = (const float*)d_in[4];
  float* out = (float*)d_out;
  char* ws = (char*)d_ws;

  build_routing<<<1, 256, 0, stream>>>(idx, w, ws);
  cvt_hidden<<<T_ * H_ / 8 / 256, 256, 0, stream>>>(hidden, ws);
  gemm1<<<dim3(I_ / 64, MAX_TILES), 256, 0, stream>>>(gup, ws);
  gemm2<<<dim3(H_ / 128, MAX_TILES), 256, 0, stream>>>(down, ws);
  combine<<<T_ * H_ / 4 / 256, 256, 0, stream>>>(out, ws);
}